// Round 8
// baseline (149.707 us; speedup 1.0000x reference)
//
#include <hip/hip_runtime.h>
#include <hip/hip_bf16.h>
#include <cstdint>
#include <cstddef>

#define BATCH   8192
#define NSAMP   8192
#define DIM     512
#define NCLASS  50000

typedef __attribute__((ext_vector_type(8)))  short bf16x8;
typedef __attribute__((ext_vector_type(4)))  float f32x4;
typedef __attribute__((ext_vector_type(16))) float f32x16;

// -log(expected_count(c)) for the log-uniform sampler, in double to match the
// numpy reference (f32 log(c+2)-log(c+1) catastrophically cancels at large c).
__device__ __forceinline__ float neg_log_expected(int c) {
    double p = log1p(1.0 / (double)(c + 1)) / log((double)(NCLASS + 1));
    double e = -expm1((double)NSAMP * log1p(-p));
    return (float)(-log(e));
}

__device__ __forceinline__ unsigned short f2bf(float f) {
    __hip_bfloat16 h = __float2bfloat16(f);
    return *reinterpret_cast<unsigned short*>(&h);
}

__device__ __forceinline__ void gload_lds16(const void* g, void* l) {
    __builtin_amdgcn_global_load_lds(
        (const __attribute__((address_space(1))) void*)g,
        (__attribute__((address_space(3))) void*)l, 16, 0, 0);
}

// ---- kernel 1: fused inputs f32->bf16 + true-logit + row_sum seed ----------
__global__ void k_fused(const float* __restrict__ inputs, const int* __restrict__ labels,
                        const float* __restrict__ W, const float* __restrict__ bias,
                        __hip_bfloat16* __restrict__ Abf,
                        float* __restrict__ true_logit, float* __restrict__ row_sum) {
    int row = blockIdx.x;
    int t   = threadIdx.x;                       // 0..127
    float4 v = reinterpret_cast<const float4*>(inputs + (size_t)row * DIM)[t];
    ushort4 u;
    u.x = f2bf(v.x); u.y = f2bf(v.y); u.z = f2bf(v.z); u.w = f2bf(v.w);
    reinterpret_cast<ushort4*>(Abf + (size_t)row * DIM)[t] = u;

    int lbl = labels[row];
    float4 w = reinterpret_cast<const float4*>(W + (size_t)lbl * DIM)[t];
    float dot = v.x * w.x + v.y * w.y + v.z * w.z + v.w * w.w;
    #pragma unroll
    for (int off = 32; off; off >>= 1) dot += __shfl_down(dot, off, 64);
    __shared__ float red[2];
    if ((t & 63) == 0) red[t >> 6] = dot;
    __syncthreads();
    if (t == 0) {
        float tl = red[0] + red[1] + bias[lbl] + neg_log_expected(lbl);
        true_logit[row] = tl;
        row_sum[row]    = __expf(tl);
    }
}

// ---- kernel 2: gather kernel[sampled] -> bf16 B; adj[s] = bias - log(expected)
__global__ void k_gather(const float* __restrict__ W, const float* __restrict__ bias,
                         const int* __restrict__ sampled,
                         __hip_bfloat16* __restrict__ Bbf, float* __restrict__ adj) {
    int s   = blockIdx.x;
    int idx = sampled[s];
    float4 v = reinterpret_cast<const float4*>(W + (size_t)idx * DIM)[threadIdx.x];
    ushort4 u;
    u.x = f2bf(v.x); u.y = f2bf(v.y); u.z = f2bf(v.z); u.w = f2bf(v.w);
    reinterpret_cast<ushort4*>(Bbf + (size_t)s * DIM)[threadIdx.x] = u;
    if (threadIdx.x == 0) adj[s] = bias[idx] + neg_log_expected(idx);
}

// ---- kernel 3: 8192x8192x512 bf16 GEMM, residency-first + cheap step -------
// Round-6 skeleton kept verbatim (4 resident blocks/CU, 2-buf BK=32,
// stage->ds_read->MFMA->__syncthreads, persistent over 4 col-tiles, XCD
// raster, involutive granule swizzle = 0 conflicts).
// Round-7 step-cost cuts (VALU 36% > MFMA 29% said issue-cost, not BW):
//  (a) 32x32x16 MFMA: 8 instead of 16 MFMA/wave-step, ~17% better pipe rate.
//      A/B use the same lane->k mapping (shared k-permutation cancels);
//      C/D layout = verified col=lane&31, row=(reg&3)+8*(reg>>2)+4*(lane>>5).
//  (b) pointer-increment staging: 4 running per-lane pointers, uniform delta
//      (+32 elems; tile-boundary jump every 16th step) vs full recompute.
__global__ __launch_bounds__(256, 4) void k_gemm(
    const __hip_bfloat16* __restrict__ A, const __hip_bfloat16* __restrict__ B,
    const float* __restrict__ adj, const int* __restrict__ labels,
    const int* __restrict__ sampled, float* __restrict__ row_sum) {
    __shared__ alignas(16) __hip_bfloat16 Asm[2][128 * 32];   // 16 KiB
    __shared__ alignas(16) __hip_bfloat16 Bsm[2][128 * 32];   // 16 KiB
    __shared__ float tsum[2][128];                            // 1 KiB

    const int tid  = threadIdx.x;
    const int wave = tid >> 6;
    const int lane = tid & 63;
    const int wr   = wave >> 1;
    const int wc   = wave & 1;

    // bid -> xcd = bid&7, u = bid>>3: rb = xcd*8 + (u&7) (A band L2-resident),
    // cgrp = u>>3 (16 groups x 4 col-tiles). Bijective, 1024 blocks.
    const int bid  = blockIdx.x;
    const int xcd  = bid & 7;
    const int u    = bid >> 3;
    const int rb   = xcd * 8 + (u & 7);
    const int cgrp = u >> 3;
    const int brow = rb * 128;

    // staging geometry (unchanged): lane covers row lane>>2 of a 16-row chunk,
    // phys granule lane&3, source granule (lane&3)^((row>>1)&3).
    const int srow = lane >> 2;
    const int sg   = (lane & 3) ^ ((lane >> 3) & 3);

    // 32x32 fragment read: row = wr*64 + mt*32 + l31; k-granule (ks*2+hi),
    // phys = granule ^ fx, fx = (l31>>1)&3 (same involution as staging).
    const int l31 = lane & 31;
    const int hi  = lane >> 5;
    const int fx  = (l31 >> 1) & 3;
    const int ph0 = (hi ^ fx) * 8;         // ks=0 granule offset (elements)
    const int ph1 = ((2 | hi) ^ fx) * 8;   // ks=1

    f32x16 acc[2][2];
    #pragma unroll
    for (int m = 0; m < 2; ++m)
        #pragma unroll
        for (int n = 0; n < 2; ++n)
            #pragma unroll
            for (int r = 0; r < 16; ++r)
                acc[m][n][r] = 0.f;

    // running staging pointers (per-lane); advance by uniform deltas
    const __hip_bfloat16* pa0 = A + (size_t)(brow + wave * 32 + srow) * DIM + sg * 8;
    const __hip_bfloat16* pa1 = pa0 + 16 * DIM;
    const __hip_bfloat16* pb0 = B + (size_t)(cgrp * 512 + wave * 32 + srow) * DIM + sg * 8;
    const __hip_bfloat16* pb1 = pb0 + 16 * DIM;

    auto stage = [&](int buf) {
        gload_lds16(pa0, &Asm[buf][(wave * 32) * 32]);
        gload_lds16(pa1, &Asm[buf][(wave * 32 + 16) * 32]);
        gload_lds16(pb0, &Bsm[buf][(wave * 32) * 32]);
        gload_lds16(pb1, &Bsm[buf][(wave * 32 + 16) * 32]);
    };
    auto advance = [&](int snext) {
        const bool tb = (snext & 15) == 0;              // next step starts a tile
        const ptrdiff_t dA = tb ? (ptrdiff_t)-480 : (ptrdiff_t)32;
        const ptrdiff_t dB = tb ? (ptrdiff_t)(128 * DIM - 480) : (ptrdiff_t)32;
        pa0 += dA; pa1 += dA; pb0 += dB; pb1 += dB;
    };

    auto body = [&](int buf) {
        bf16x8 a[2][2], b[2][2];
        #pragma unroll
        for (int mt = 0; mt < 2; ++mt) {
            const int rbase = (wr * 64 + mt * 32 + l31) * 32;
            a[mt][0] = *reinterpret_cast<const bf16x8*>(&Asm[buf][rbase + ph0]);
            a[mt][1] = *reinterpret_cast<const bf16x8*>(&Asm[buf][rbase + ph1]);
        }
        #pragma unroll
        for (int nt = 0; nt < 2; ++nt) {
            const int rbase = (wc * 64 + nt * 32 + l31) * 32;
            b[nt][0] = *reinterpret_cast<const bf16x8*>(&Bsm[buf][rbase + ph0]);
            b[nt][1] = *reinterpret_cast<const bf16x8*>(&Bsm[buf][rbase + ph1]);
        }
        #pragma unroll
        for (int mt = 0; mt < 2; ++mt)
            #pragma unroll
            for (int nt = 0; nt < 2; ++nt)
                #pragma unroll
                for (int ks = 0; ks < 2; ++ks)
                    acc[mt][nt] = __builtin_amdgcn_mfma_f32_32x32x16_bf16(
                        a[mt][ks], b[nt][ks], acc[mt][nt], 0, 0, 0);
    };

    // epilogue for tile t: logit = acc + adj[col]; mask label==sampled; exp;
    // 32-lane reduce per row; combine col-waves via tsum; one atomic per row.
    auto epi = [&](int t) {
        const int bcol = (cgrp * 4 + t) * 128;
        float aadj[2]; int sv[2];
        #pragma unroll
        for (int nt = 0; nt < 2; ++nt) {
            int col = bcol + wc * 64 + nt * 32 + l31;
            aadj[nt] = adj[col];
            sv[nt]   = sampled[col];
        }
        #pragma unroll
        for (int mt = 0; mt < 2; ++mt) {
            #pragma unroll
            for (int r = 0; r < 16; ++r) {
                const int lrow = wr * 64 + mt * 32 + (r & 3) + 8 * (r >> 2) + 4 * hi;
                const int lbl  = labels[brow + lrow];
                float part = 0.f;
                #pragma unroll
                for (int nt = 0; nt < 2; ++nt) {
                    float logit = acc[mt][nt][r] + aadj[nt];
                    part += (sv[nt] == lbl) ? 0.f : __expf(logit);
                }
                part += __shfl_xor(part, 1, 32);
                part += __shfl_xor(part, 2, 32);
                part += __shfl_xor(part, 4, 32);
                part += __shfl_xor(part, 8, 32);
                part += __shfl_xor(part, 16, 32);
                if (l31 == 0) tsum[wc][lrow] = part;   // lanes 0 & 32: diff rows
            }
        }
        __syncthreads();
        if (tid < 128)
            atomicAdd(&row_sum[brow + tid], tsum[0][tid] + tsum[1][tid]);
        #pragma unroll
        for (int m = 0; m < 2; ++m)
            #pragma unroll
            for (int n = 0; n < 2; ++n)
                #pragma unroll
                for (int r = 0; r < 16; ++r)
                    acc[m][n][r] = 0.f;
    };

    stage(0);
    advance(1);
    __syncthreads();

    #pragma unroll 1
    for (int g = 0; g < 64; ++g) {
        if (g < 63) { stage((g + 1) & 1); advance(g + 2); }
        body(g & 1);
        if ((g & 15) == 15) epi(g >> 4);
        __syncthreads();                  // drains vmcnt: stage(g+1) ready
    }
}

// ---- kernel 4: loss = log(row_sum) - true_logit -----------------------------
__global__ void k_final(const float* __restrict__ row_sum,
                        const float* __restrict__ true_logit,
                        float* __restrict__ loss) {
    int i = blockIdx.x * blockDim.x + threadIdx.x;
    loss[i] = logf(row_sum[i]) - true_logit[i];
}

extern "C" void kernel_launch(void* const* d_in, const int* in_sizes, int n_in,
                              void* d_out, int out_size, void* d_ws, size_t ws_size,
                              hipStream_t stream) {
    const float* inputs  = (const float*)d_in[0];
    const int*   labels  = (const int*)d_in[1];
    const float* W       = (const float*)d_in[2];
    const float* bias    = (const float*)d_in[3];
    const int*   sampled = (const int*)d_in[4];
    float*       loss    = (float*)d_out;

    char* ws = (char*)d_ws;
    __hip_bfloat16* Abf = (__hip_bfloat16*)ws;                                  // 8 MiB
    __hip_bfloat16* Bbf = (__hip_bfloat16*)(ws + (size_t)BATCH * DIM * 2);      // 8 MiB
    float* adj        = (float*)(ws + (size_t)(BATCH + NSAMP) * DIM * 2);       // 32 KiB
    float* true_logit = adj + NSAMP;                                            // 32 KiB
    float* row_sum    = true_logit + BATCH;                                     // 32 KiB

    hipLaunchKernelGGL(k_fused, dim3(BATCH), dim3(128), 0, stream,
                       inputs, labels, W, bias, Abf, true_logit, row_sum);
    hipLaunchKernelGGL(k_gather, dim3(NSAMP), dim3(128), 0, stream,
                       W, bias, sampled, Bbf, adj);
    hipLaunchKernelGGL(k_gemm, dim3(1024), dim3(256), 0, stream,
                       Abf, Bbf, adj, labels, sampled, row_sum);
    hipLaunchKernelGGL(k_final, dim3(BATCH / 256), dim3(256), 0, stream,
                       row_sum, true_logit, loss);
}

// Round 9
// 136.797 us; speedup vs baseline: 1.0944x; 1.0944x over previous
//
#include <hip/hip_runtime.h>
#include <hip/hip_bf16.h>
#include <cstdint>
#include <cstddef>

#define BATCH   8192
#define NSAMP   8192
#define DIM     512
#define NCLASS  50000

typedef __attribute__((ext_vector_type(8))) short bf16x8;
typedef __attribute__((ext_vector_type(4))) float f32x4;

// -log(expected_count(c)) for the log-uniform sampler, in double to match the
// numpy reference (f32 log(c+2)-log(c+1) catastrophically cancels at large c).
__device__ __forceinline__ float neg_log_expected(int c) {
    double p = log1p(1.0 / (double)(c + 1)) / log((double)(NCLASS + 1));
    double e = -expm1((double)NSAMP * log1p(-p));
    return (float)(-log(e));
}

__device__ __forceinline__ unsigned short f2bf(float f) {
    __hip_bfloat16 h = __float2bfloat16(f);
    return *reinterpret_cast<unsigned short*>(&h);
}

__device__ __forceinline__ void gload_lds16(const void* g, void* l) {
    __builtin_amdgcn_global_load_lds(
        (const __attribute__((address_space(1))) void*)g,
        (__attribute__((address_space(3))) void*)l, 16, 0, 0);
}

// ---- kernel 1: fused inputs f32->bf16 + true-logit + row_sum seed ----------
__global__ void k_fused(const float* __restrict__ inputs, const int* __restrict__ labels,
                        const float* __restrict__ W, const float* __restrict__ bias,
                        __hip_bfloat16* __restrict__ Abf,
                        float* __restrict__ true_logit, float* __restrict__ row_sum) {
    int row = blockIdx.x;
    int t   = threadIdx.x;                       // 0..127
    float4 v = reinterpret_cast<const float4*>(inputs + (size_t)row * DIM)[t];
    ushort4 u;
    u.x = f2bf(v.x); u.y = f2bf(v.y); u.z = f2bf(v.z); u.w = f2bf(v.w);
    reinterpret_cast<ushort4*>(Abf + (size_t)row * DIM)[t] = u;

    int lbl = labels[row];
    float4 w = reinterpret_cast<const float4*>(W + (size_t)lbl * DIM)[t];
    float dot = v.x * w.x + v.y * w.y + v.z * w.z + v.w * w.w;
    #pragma unroll
    for (int off = 32; off; off >>= 1) dot += __shfl_down(dot, off, 64);
    __shared__ float red[2];
    if ((t & 63) == 0) red[t >> 6] = dot;
    __syncthreads();
    if (t == 0) {
        float tl = red[0] + red[1] + bias[lbl] + neg_log_expected(lbl);
        true_logit[row] = tl;
        row_sum[row]    = __expf(tl);
    }
}

// ---- kernel 2: gather kernel[sampled] -> bf16 B; adj[s] = bias - log(expected)
__global__ void k_gather(const float* __restrict__ W, const float* __restrict__ bias,
                         const int* __restrict__ sampled,
                         __hip_bfloat16* __restrict__ Bbf, float* __restrict__ adj) {
    int s   = blockIdx.x;
    int idx = sampled[s];
    float4 v = reinterpret_cast<const float4*>(W + (size_t)idx * DIM)[threadIdx.x];
    ushort4 u;
    u.x = f2bf(v.x); u.y = f2bf(v.y); u.z = f2bf(v.z); u.w = f2bf(v.w);
    reinterpret_cast<ushort4*>(Bbf + (size_t)s * DIM)[threadIdx.x] = u;
    if (threadIdx.x == 0) adj[s] = bias[idx] + neg_log_expected(idx);
}

// ---- kernel 3: 8192x8192x512 bf16 GEMM, max-residency -----------------------
// Round-8: round-6 skeleton (proven: 2-buf BK=32 stage->read->MFMA->sync,
// persistent 4 col-tiles, XCD raster, involutive granule swizzle, 16x16x32
// read pattern = measured 0 conflicts) with the 128x128 tile re-decomposed
// into 8 WAVES x (32x64 out) instead of 4 x (64x64): per-wave regs ~halved
// (acc 32 vs 64) -> 3-4 blocks x 8 waves = 24-32 waves/CU (was 13-16).
// Round-7's pointer-increment staging kept (VALUBusy 36.7 -> 26.9 measured);
// round-7's 32x32 MFMA reverted (it re-introduced 8.4M bank conflicts).
__global__ __launch_bounds__(512, 6) void k_gemm(
    const __hip_bfloat16* __restrict__ A, const __hip_bfloat16* __restrict__ B,
    const float* __restrict__ adj, const int* __restrict__ labels,
    const int* __restrict__ sampled, float* __restrict__ row_sum) {
    __shared__ alignas(16) __hip_bfloat16 Asm[2][128 * 32];   // 16 KiB
    __shared__ alignas(16) __hip_bfloat16 Bsm[2][128 * 32];   // 16 KiB
    __shared__ float tsum[2][128];                            // 1 KiB

    const int tid  = threadIdx.x;
    const int wave = tid >> 6;           // 0..7
    const int lane = tid & 63;
    const int wm   = wave >> 1;          // 0..3 (M quarter: 32 rows)
    const int wn   = wave & 1;           // 0..1 (N half: 64 cols)

    // bid -> xcd = bid&7, u = bid>>3: rb = xcd*8 + (u&7) (A band L2-resident),
    // cgrp = u>>3 (16 groups x 4 col-tiles). Bijective, 1024 blocks.
    const int bid  = blockIdx.x;
    const int xcd  = bid & 7;
    const int u    = bid >> 3;
    const int rb   = xcd * 8 + (u & 7);
    const int cgrp = u >> 3;
    const int brow = rb * 128;

    // staging: wave w covers 16 rows [w*16, w*16+16); lane covers row lane>>2,
    // phys granule lane&3, source granule (lane&3)^((row>>1)&3)  (w*16 = 0 mod 8
    // so the involution depends only on srow).
    const int srow = lane >> 2;
    const int sg   = (lane & 3) ^ ((lane >> 3) & 3);
    // fragment read (proven 0-conflict): row = ...+rsel, phys granule =
    // (lane>>4) ^ ((rsel>>1)&3)
    const int rsel = lane & 15;
    const int koff = ((lane >> 4) ^ ((lane >> 1) & 3)) * 8;

    f32x4 acc[2][4];
    #pragma unroll
    for (int m = 0; m < 2; ++m)
        #pragma unroll
        for (int n = 0; n < 4; ++n)
            acc[m][n] = (f32x4){0.f, 0.f, 0.f, 0.f};

    // running staging pointers (per-lane), uniform bumps
    const __hip_bfloat16* pa = A + (size_t)(brow + wave * 16 + srow) * DIM + sg * 8;
    const __hip_bfloat16* pb = B + (size_t)(cgrp * 512 + wave * 16 + srow) * DIM + sg * 8;

    auto stage = [&](int buf) {
        gload_lds16(pa, &Asm[buf][(wave * 16) * 32]);
        gload_lds16(pb, &Bsm[buf][(wave * 16) * 32]);
    };
    auto advance = [&](int snext) {
        const bool tb = (snext & 15) == 0;              // next step starts a tile
        const ptrdiff_t dA = tb ? (ptrdiff_t)-480 : (ptrdiff_t)32;
        const ptrdiff_t dB = tb ? (ptrdiff_t)(128 * DIM - 480) : (ptrdiff_t)32;
        pa += dA; pb += dB;
    };

    auto body = [&](int buf) {
        bf16x8 a[2], b[4];
        #pragma unroll
        for (int m = 0; m < 2; ++m)
            a[m] = *reinterpret_cast<const bf16x8*>(
                &Asm[buf][(wm * 32 + m * 16 + rsel) * 32 + koff]);
        #pragma unroll
        for (int n = 0; n < 4; ++n)
            b[n] = *reinterpret_cast<const bf16x8*>(
                &Bsm[buf][(wn * 64 + n * 16 + rsel) * 32 + koff]);
        #pragma unroll
        for (int m = 0; m < 2; ++m)
            #pragma unroll
            for (int n = 0; n < 4; ++n)
                acc[m][n] = __builtin_amdgcn_mfma_f32_16x16x32_bf16(a[m], b[n], acc[m][n], 0, 0, 0);
    };

    // epilogue for tile t: logit = acc + adj[col]; mask; exp; 16-lane row
    // reduce; combine the 2 col-waves via tsum; one atomic per row.
    auto epi = [&](int t) {
        const int bcol = (cgrp * 4 + t) * 128;
        int sv[4]; float aadj[4];
        #pragma unroll
        for (int n = 0; n < 4; ++n) {
            int col = bcol + wn * 64 + n * 16 + rsel;
            aadj[n] = adj[col];
            sv[n]   = sampled[col];
        }
        #pragma unroll
        for (int m = 0; m < 2; ++m) {
            #pragma unroll
            for (int r = 0; r < 4; ++r) {
                int lr  = wm * 32 + m * 16 + (lane >> 4) * 4 + r;
                int lbl = labels[brow + lr];
                float part = 0.f;
                #pragma unroll
                for (int n = 0; n < 4; ++n) {
                    float logit = acc[m][n][r] + aadj[n];
                    part += (sv[n] == lbl) ? 0.f : __expf(logit);
                }
                part += __shfl_xor(part, 1, 16);
                part += __shfl_xor(part, 2, 16);
                part += __shfl_xor(part, 4, 16);
                part += __shfl_xor(part, 8, 16);
                if (rsel == 0) tsum[wn][lr] = part;
            }
        }
        __syncthreads();
        if (tid < 128)
            atomicAdd(&row_sum[brow + tid], tsum[0][tid] + tsum[1][tid]);
        #pragma unroll
        for (int m = 0; m < 2; ++m)
            #pragma unroll
            for (int n = 0; n < 4; ++n)
                acc[m][n] = (f32x4){0.f, 0.f, 0.f, 0.f};
    };

    stage(0);
    advance(1);
    __syncthreads();

    #pragma unroll 1
    for (int g = 0; g < 64; ++g) {
        if (g < 63) { stage((g + 1) & 1); advance(g + 2); }
        body(g & 1);
        if ((g & 15) == 15) epi(g >> 4);
        __syncthreads();                  // drains vmcnt: stage(g+1) ready
    }
}

// ---- kernel 4: loss = log(row_sum) - true_logit -----------------------------
__global__ void k_final(const float* __restrict__ row_sum,
                        const float* __restrict__ true_logit,
                        float* __restrict__ loss) {
    int i = blockIdx.x * blockDim.x + threadIdx.x;
    loss[i] = logf(row_sum[i]) - true_logit[i];
}

extern "C" void kernel_launch(void* const* d_in, const int* in_sizes, int n_in,
                              void* d_out, int out_size, void* d_ws, size_t ws_size,
                              hipStream_t stream) {
    const float* inputs  = (const float*)d_in[0];
    const int*   labels  = (const int*)d_in[1];
    const float* W       = (const float*)d_in[2];
    const float* bias    = (const float*)d_in[3];
    const int*   sampled = (const int*)d_in[4];
    float*       loss    = (float*)d_out;

    char* ws = (char*)d_ws;
    __hip_bfloat16* Abf = (__hip_bfloat16*)ws;                                  // 8 MiB
    __hip_bfloat16* Bbf = (__hip_bfloat16*)(ws + (size_t)BATCH * DIM * 2);      // 8 MiB
    float* adj        = (float*)(ws + (size_t)(BATCH + NSAMP) * DIM * 2);       // 32 KiB
    float* true_logit = adj + NSAMP;                                            // 32 KiB
    float* row_sum    = true_logit + BATCH;                                     // 32 KiB

    hipLaunchKernelGGL(k_fused, dim3(BATCH), dim3(128), 0, stream,
                       inputs, labels, W, bias, Abf, true_logit, row_sum);
    hipLaunchKernelGGL(k_gather, dim3(NSAMP), dim3(128), 0, stream,
                       W, bias, sampled, Bbf, adj);
    hipLaunchKernelGGL(k_gemm, dim3(1024), dim3(512), 0, stream,
                       Abf, Bbf, adj, labels, sampled, row_sum);
    hipLaunchKernelGGL(k_final, dim3(BATCH / 256), dim3(256), 0, stream,
                       row_sum, true_logit, loss);
}

// Round 10
// 130.406 us; speedup vs baseline: 1.1480x; 1.0490x over previous
//
#include <hip/hip_runtime.h>
#include <hip/hip_bf16.h>
#include <cstdint>
#include <cstddef>

#define BATCH   8192
#define NSAMP   8192
#define DIM     512
#define NCLASS  50000

typedef __attribute__((ext_vector_type(8))) short bf16x8;
typedef __attribute__((ext_vector_type(4))) float f32x4;

// -log(expected_count(c)) for the log-uniform sampler, in double to match the
// numpy reference (f32 log(c+2)-log(c+1) catastrophically cancels at large c).
__device__ __forceinline__ float neg_log_expected(int c) {
    double p = log1p(1.0 / (double)(c + 1)) / log((double)(NCLASS + 1));
    double e = -expm1((double)NSAMP * log1p(-p));
    return (float)(-log(e));
}

__device__ __forceinline__ unsigned short f2bf(float f) {
    __hip_bfloat16 h = __float2bfloat16(f);
    return *reinterpret_cast<unsigned short*>(&h);
}

__device__ __forceinline__ void gload_lds16(const void* g, void* l) {
    __builtin_amdgcn_global_load_lds(
        (const __attribute__((address_space(1))) void*)g,
        (__attribute__((address_space(3))) void*)l, 16, 0, 0);
}

// ---- kernel 1: fused prep ---------------------------------------------------
// blocks [0,BATCH): inputs f32->bf16 + true-logit + row_sum seed
// blocks [BATCH,BATCH+NSAMP): gather kernel[sampled]->bf16 B + adj
__global__ void k_prep(const float* __restrict__ inputs, const int* __restrict__ labels,
                       const float* __restrict__ W, const float* __restrict__ bias,
                       const int* __restrict__ sampled,
                       __hip_bfloat16* __restrict__ Abf, __hip_bfloat16* __restrict__ Bbf,
                       float* __restrict__ adj,
                       float* __restrict__ true_logit, float* __restrict__ row_sum) {
    int bid = blockIdx.x;
    int t   = threadIdx.x;                       // 0..127
    if (bid < BATCH) {
        int row = bid;
        float4 v = reinterpret_cast<const float4*>(inputs + (size_t)row * DIM)[t];
        ushort4 u;
        u.x = f2bf(v.x); u.y = f2bf(v.y); u.z = f2bf(v.z); u.w = f2bf(v.w);
        reinterpret_cast<ushort4*>(Abf + (size_t)row * DIM)[t] = u;

        int lbl = labels[row];
        float4 w = reinterpret_cast<const float4*>(W + (size_t)lbl * DIM)[t];
        float dot = v.x * w.x + v.y * w.y + v.z * w.z + v.w * w.w;
        #pragma unroll
        for (int off = 32; off; off >>= 1) dot += __shfl_down(dot, off, 64);
        __shared__ float red[2];
        if ((t & 63) == 0) red[t >> 6] = dot;
        __syncthreads();
        if (t == 0) {
            float tl = red[0] + red[1] + bias[lbl] + neg_log_expected(lbl);
            true_logit[row] = tl;
            row_sum[row]    = __expf(tl);
        }
    } else {
        int s   = bid - BATCH;
        int idx = sampled[s];
        float4 v = reinterpret_cast<const float4*>(W + (size_t)idx * DIM)[t];
        ushort4 u;
        u.x = f2bf(v.x); u.y = f2bf(v.y); u.z = f2bf(v.z); u.w = f2bf(v.w);
        reinterpret_cast<ushort4*>(Bbf + (size_t)s * DIM)[t] = u;
        if (t == 0) adj[s] = bias[idx] + neg_log_expected(idx);
    }
}

// ---- kernel 2: 8192x8192x512 bf16 GEMM: lead-2 pipeline x high residency ----
// Round-9: rounds 6/8 proved residency is binding but their step floor was the
// stage latency (stage(g+1) issued and vmcnt(0)-drained in the SAME step).
// Fix: 3 LDS buffers, stage issued 2 steps ahead, per-step VMCNT(2) + raw
// s_barrier (round-1's proven ledger), epilogue barrier waits lgkm only.
// Kept: 8-wave 32x64 decomposition (VGPR 36), involutive granule swizzle +
// 16x16x32 read pattern (0 conflicts measured), pointer-bump staging,
// persistence over 4 col-tiles, XCD raster. LDS 50KB -> 3 blocks/CU = 24 waves.
//
// vmcnt ledger (per wave, 2 loads/stage): steady outstanding at the wait =
// {stage g, stage g+1} = 4 -> VMCNT(2) retires stage g (2 steps of cover).
// epi (6 loads + atomic) only over-drains at the 4 tile boundaries: its ops
// are NEWER than any stage the next steps need, so correctness holds; g=63
// peeled with VMCNT(0).

#define BARRIER()  asm volatile("s_barrier" ::: "memory")
#define LBARRIER() asm volatile("s_waitcnt lgkmcnt(0)\n\ts_barrier" ::: "memory")
#define VMCNT(n)   asm volatile("s_waitcnt vmcnt(" #n ")" ::: "memory")

__global__ __launch_bounds__(512, 6) void k_gemm(
    const __hip_bfloat16* __restrict__ A, const __hip_bfloat16* __restrict__ B,
    const float* __restrict__ adj, const int* __restrict__ labels,
    const int* __restrict__ sampled, float* __restrict__ row_sum) {
    __shared__ alignas(16) __hip_bfloat16 Asm[3][128 * 32];   // 24 KiB
    __shared__ alignas(16) __hip_bfloat16 Bsm[3][128 * 32];   // 24 KiB
    __shared__ float tsum[2][128];                            // 1 KiB

    const int tid  = threadIdx.x;
    const int wave = tid >> 6;           // 0..7
    const int lane = tid & 63;
    const int wm   = wave >> 1;          // 0..3 (M quarter: 32 rows)
    const int wn   = wave & 1;           // 0..1 (N half: 64 cols)

    // bid -> xcd = bid&7, u = bid>>3: rb = xcd*8 + (u&7) (A band L2-resident),
    // cgrp = u>>3 (16 groups x 4 col-tiles). Bijective, 1024 blocks.
    const int bid  = blockIdx.x;
    const int xcd  = bid & 7;
    const int u    = bid >> 3;
    const int rb   = xcd * 8 + (u & 7);
    const int cgrp = u >> 3;
    const int brow = rb * 128;

    // staging: wave w covers rows [w*16, w*16+16); lane -> row lane>>2, phys
    // granule lane&3, source granule (lane&3)^((row>>1)&3) (w*16 == 0 mod 8).
    const int srow = lane >> 2;
    const int sg   = (lane & 3) ^ ((lane >> 3) & 3);
    // fragment read (proven 0-conflict): phys granule = (lane>>4)^((rsel>>1)&3)
    const int rsel = lane & 15;
    const int koff = ((lane >> 4) ^ ((lane >> 1) & 3)) * 8;

    f32x4 acc[2][4];
    #pragma unroll
    for (int m = 0; m < 2; ++m)
        #pragma unroll
        for (int n = 0; n < 4; ++n)
            acc[m][n] = (f32x4){0.f, 0.f, 0.f, 0.f};

    // running staging pointers (per-lane), uniform bumps
    const __hip_bfloat16* pa = A + (size_t)(brow + wave * 16 + srow) * DIM + sg * 8;
    const __hip_bfloat16* pb = B + (size_t)(cgrp * 512 + wave * 16 + srow) * DIM + sg * 8;

    auto stage = [&](int buf) {
        gload_lds16(pa, &Asm[buf][(wave * 16) * 32]);
        gload_lds16(pb, &Bsm[buf][(wave * 16) * 32]);
    };
    auto advance = [&](int snext) {
        const bool tb = (snext & 15) == 0;              // next step starts a tile
        const ptrdiff_t dA = tb ? (ptrdiff_t)-480 : (ptrdiff_t)32;
        const ptrdiff_t dB = tb ? (ptrdiff_t)(128 * DIM - 480) : (ptrdiff_t)32;
        pa += dA; pb += dB;
    };

    auto body = [&](int buf) {
        bf16x8 a[2], b[4];
        #pragma unroll
        for (int m = 0; m < 2; ++m)
            a[m] = *reinterpret_cast<const bf16x8*>(
                &Asm[buf][(wm * 32 + m * 16 + rsel) * 32 + koff]);
        #pragma unroll
        for (int n = 0; n < 4; ++n)
            b[n] = *reinterpret_cast<const bf16x8*>(
                &Bsm[buf][(wn * 64 + n * 16 + rsel) * 32 + koff]);
        #pragma unroll
        for (int m = 0; m < 2; ++m)
            #pragma unroll
            for (int n = 0; n < 4; ++n)
                acc[m][n] = __builtin_amdgcn_mfma_f32_16x16x32_bf16(a[m], b[n], acc[m][n], 0, 0, 0);
    };

    // epilogue for tile t; barrier waits lgkm ONLY (staging stays in flight)
    auto epi = [&](int t) {
        const int bcol = (cgrp * 4 + t) * 128;
        int sv[4]; float aadj[4];
        #pragma unroll
        for (int n = 0; n < 4; ++n) {
            int col = bcol + wn * 64 + n * 16 + rsel;
            aadj[n] = adj[col];
            sv[n]   = sampled[col];
        }
        #pragma unroll
        for (int m = 0; m < 2; ++m) {
            #pragma unroll
            for (int r = 0; r < 4; ++r) {
                int lr  = wm * 32 + m * 16 + (lane >> 4) * 4 + r;
                int lbl = labels[brow + lr];
                float part = 0.f;
                #pragma unroll
                for (int n = 0; n < 4; ++n) {
                    float logit = acc[m][n][r] + aadj[n];
                    part += (sv[n] == lbl) ? 0.f : __expf(logit);
                }
                part += __shfl_xor(part, 1, 16);
                part += __shfl_xor(part, 2, 16);
                part += __shfl_xor(part, 4, 16);
                part += __shfl_xor(part, 8, 16);
                if (rsel == 0) tsum[wn][lr] = part;
            }
        }
        LBARRIER();
        if (tid < 128)
            atomicAdd(&row_sum[brow + tid], tsum[0][tid] + tsum[1][tid]);
        #pragma unroll
        for (int m = 0; m < 2; ++m)
            #pragma unroll
            for (int n = 0; n < 4; ++n)
                acc[m][n] = (f32x4){0.f, 0.f, 0.f, 0.f};
    };

    // prologue: lead-2
    stage(0); advance(1);
    stage(1); advance(2);

    #pragma unroll 1
    for (int g = 0; g < 63; ++g) {
        VMCNT(2);                         // stage g complete (g+1 in flight)
        BARRIER();                        // all waves' stage g landed
        const int cur = g % 3;
        if (g < 62) { stage((g + 2) % 3); advance(g + 3); }
        body(cur);
        if ((g & 15) == 15) epi(g >> 4);  // tiles 0..2 (g = 15, 31, 47)
    }
    // peeled last step: g = 63, buf 63%3 = 0
    VMCNT(0);
    BARRIER();
    body(0);
    epi(3);
}

// ---- kernel 3: loss = log(row_sum) - true_logit -----------------------------
__global__ void k_final(const float* __restrict__ row_sum,
                        const float* __restrict__ true_logit,
                        float* __restrict__ loss) {
    int i = blockIdx.x * blockDim.x + threadIdx.x;
    loss[i] = logf(row_sum[i]) - true_logit[i];
}

extern "C" void kernel_launch(void* const* d_in, const int* in_sizes, int n_in,
                              void* d_out, int out_size, void* d_ws, size_t ws_size,
                              hipStream_t stream) {
    const float* inputs  = (const float*)d_in[0];
    const int*   labels  = (const int*)d_in[1];
    const float* W       = (const float*)d_in[2];
    const float* bias    = (const float*)d_in[3];
    const int*   sampled = (const int*)d_in[4];
    float*       loss    = (float*)d_out;

    char* ws = (char*)d_ws;
    __hip_bfloat16* Abf = (__hip_bfloat16*)ws;                                  // 8 MiB
    __hip_bfloat16* Bbf = (__hip_bfloat16*)(ws + (size_t)BATCH * DIM * 2);      // 8 MiB
    float* adj        = (float*)(ws + (size_t)(BATCH + NSAMP) * DIM * 2);       // 32 KiB
    float* true_logit = adj + NSAMP;                                            // 32 KiB
    float* row_sum    = true_logit + BATCH;                                     // 32 KiB

    hipLaunchKernelGGL(k_prep, dim3(BATCH + NSAMP), dim3(128), 0, stream,
                       inputs, labels, W, bias, sampled, Abf, Bbf, adj,
                       true_logit, row_sum);
    hipLaunchKernelGGL(k_gemm, dim3(1024), dim3(512), 0, stream,
                       Abf, Bbf, adj, labels, sampled, row_sum);
    hipLaunchKernelGGL(k_final, dim3(BATCH / 256), dim3(256), 0, stream,
                       row_sum, true_logit, loss);
}

// Round 11
// 125.945 us; speedup vs baseline: 1.1887x; 1.0354x over previous
//
#include <hip/hip_runtime.h>
#include <hip/hip_bf16.h>
#include <cstdint>
#include <cstddef>

#define BATCH   8192
#define NSAMP   8192
#define DIM     512
#define NCLASS  50000
#define HBINS   50176    // 256 blocks * 196 bins >= NCLASS

typedef __attribute__((ext_vector_type(8))) short bf16x8;
typedef __attribute__((ext_vector_type(4))) float f32x4;

// -log(expected_count(c)) for the log-uniform sampler, in double to match the
// numpy reference (f32 log(c+2)-log(c+1) catastrophically cancels at large c).
__device__ __forceinline__ float neg_log_expected(int c) {
    double p = log1p(1.0 / (double)(c + 1)) / log((double)(NCLASS + 1));
    double e = -expm1((double)NSAMP * log1p(-p));
    return (float)(-log(e));
}

__device__ __forceinline__ unsigned short f2bf(float f) {
    __hip_bfloat16 h = __float2bfloat16(f);
    return *reinterpret_cast<unsigned short*>(&h);
}

__device__ __forceinline__ void gload_lds16(const void* g, void* l) {
    __builtin_amdgcn_global_load_lds(
        (const __attribute__((address_space(1))) void*)g,
        (__attribute__((address_space(3))) void*)l, 16, 0, 0);
}

// ==== dedupe pipeline (deterministic: scan-based, no atomic ordering) =======
__global__ void k_zero(int* __restrict__ hist) {
    hist[blockIdx.x * 1024 + threadIdx.x] = 0;
}
__global__ void k_hist(const int* __restrict__ sampled, int* __restrict__ hist) {
    atomicAdd(&hist[sampled[blockIdx.x * 1024 + threadIdx.x]], 1);
}
// per-block distinct counts (256 blocks x 196 bins)
__global__ void k_scan1(const int* __restrict__ hist, int* __restrict__ btot) {
    int b = blockIdx.x, t = threadIdx.x;
    int c = b * 196 + t;
    int x = (t < 196 && c < NCLASS && hist[c] > 0) ? 1 : 0;
    int lane = t & 63, wv = t >> 6;
    #pragma unroll
    for (int off = 32; off; off >>= 1) x += __shfl_down(x, off, 64);
    __shared__ int ws[4];
    if (lane == 0) ws[wv] = x;
    __syncthreads();
    if (t == 0) btot[b] = ws[0] + ws[1] + ws[2] + ws[3];
}
// exclusive scan of the 256 block totals; meta = {D, padD}
__global__ void k_scan2(const int* __restrict__ btot, int* __restrict__ boff,
                        int* __restrict__ meta) {
    int t = threadIdx.x;
    int v = btot[t];
    int lane = t & 63, wv = t >> 6;
    int x = v;
    #pragma unroll
    for (int off = 1; off < 64; off <<= 1) {
        int y = __shfl_up(x, off, 64);
        if (lane >= off) x += y;
    }
    __shared__ int ws[4];
    if (lane == 63) ws[wv] = x;
    __syncthreads();
    int base = 0;
    for (int w = 0; w < wv; ++w) base += ws[w];
    boff[t] = base + x - v;
    if (t == 255) {
        int D = base + x;
        meta[0] = D;
        meta[1] = (D + 127) & ~127;
    }
}
// scatter distinct class ids to compact positions (deterministic)
__global__ void k_scatter(const int* __restrict__ hist, const int* __restrict__ boff,
                          int* __restrict__ didx) {
    int b = blockIdx.x, t = threadIdx.x;
    int c = b * 196 + t;
    int ind = (t < 196 && c < NCLASS && hist[c] > 0) ? 1 : 0;
    int lane = t & 63, wv = t >> 6;
    int x = ind;
    #pragma unroll
    for (int off = 1; off < 64; off <<= 1) {
        int y = __shfl_up(x, off, 64);
        if (lane >= off) x += y;
    }
    __shared__ int ws[4];
    if (lane == 63) ws[wv] = x;
    __syncthreads();
    int base = boff[b];
    for (int w = 0; w < wv; ++w) base += ws[w];
    if (ind) didx[base + x - 1] = c;
}

// ==== prep: A-convert + true-logit + seed  |  distinct-B gather + adjD ======
// blocks [0,BATCH): inputs f32->bf16; true logit; row_sum seed = (1-m)*exp(tl)
//   (m = hist[label]: subtracts the m masked duplicate columns the GEMM adds)
// blocks [BATCH, ...): s = bid-BATCH < D: gather W[didx[s]] -> bf16, adjD[s] =
//   bias + nle + ln(m);  D<=s<padD: zero row, adjD = -1e5 (exp -> 0)
__global__ void k_prep(const float* __restrict__ inputs, const int* __restrict__ labels,
                       const float* __restrict__ W, const float* __restrict__ bias,
                       const int* __restrict__ hist, const int* __restrict__ didx,
                       const int* __restrict__ meta,
                       __hip_bfloat16* __restrict__ Abf, __hip_bfloat16* __restrict__ Bbf,
                       float* __restrict__ adj,
                       float* __restrict__ true_logit, float* __restrict__ row_sum) {
    int bid = blockIdx.x;
    int t   = threadIdx.x;                       // 0..127
    if (bid < BATCH) {
        int row = bid;
        float4 v = reinterpret_cast<const float4*>(inputs + (size_t)row * DIM)[t];
        ushort4 u;
        u.x = f2bf(v.x); u.y = f2bf(v.y); u.z = f2bf(v.z); u.w = f2bf(v.w);
        reinterpret_cast<ushort4*>(Abf + (size_t)row * DIM)[t] = u;

        int lbl = labels[row];
        float4 w = reinterpret_cast<const float4*>(W + (size_t)lbl * DIM)[t];
        float dot = v.x * w.x + v.y * w.y + v.z * w.z + v.w * w.w;
        #pragma unroll
        for (int off = 32; off; off >>= 1) dot += __shfl_down(dot, off, 64);
        __shared__ float red[2];
        if ((t & 63) == 0) red[t >> 6] = dot;
        __syncthreads();
        if (t == 0) {
            float tl = red[0] + red[1] + bias[lbl] + neg_log_expected(lbl);
            true_logit[row] = tl;
            row_sum[row]    = (1.0f - (float)hist[lbl]) * __expf(tl);
        }
    } else {
        int s = bid - BATCH;
        int D = meta[0], padD = meta[1];
        if (s >= padD) return;
        if (s < D) {
            int idx = didx[s];
            float4 v = reinterpret_cast<const float4*>(W + (size_t)idx * DIM)[t];
            ushort4 u;
            u.x = f2bf(v.x); u.y = f2bf(v.y); u.z = f2bf(v.z); u.w = f2bf(v.w);
            reinterpret_cast<ushort4*>(Bbf + (size_t)s * DIM)[t] = u;
            if (t == 0)
                adj[s] = bias[idx] + neg_log_expected(idx) + logf((float)hist[idx]);
        } else {
            ushort4 z; z.x = z.y = z.z = z.w = 0;
            reinterpret_cast<ushort4*>(Bbf + (size_t)s * DIM)[t] = z;
            if (t == 0) adj[s] = -100000.0f;
        }
    }
}

// ==== GEMM: round-6 structure (best measured), N = padD distinct cols =======
// 128x128 tile, BK=32, 4 waves (2x2), 2-buf stage->read->MFMA->__syncthreads,
// 4 resident blocks/CU, involutive granule swizzle (0 conflicts), XCD raster.
// Col-tiles strided by 16 across the 16 cgrps so ALL 1024 blocks stay active
// at nct ~ 27-32. No hit-mask (handled by seed); weight ln(m) folded in adjD.
__global__ __launch_bounds__(256, 4) void k_gemm(
    const __hip_bfloat16* __restrict__ A, const __hip_bfloat16* __restrict__ B,
    const float* __restrict__ adj, const int* __restrict__ labels,
    const int* __restrict__ meta, float* __restrict__ row_sum) {
    __shared__ alignas(16) __hip_bfloat16 Asm[2][128 * 32];   // 16 KiB
    __shared__ alignas(16) __hip_bfloat16 Bsm[2][128 * 32];   // 16 KiB
    __shared__ float tsum[2][128];                            // 1 KiB

    const int tid  = threadIdx.x;
    const int wave = tid >> 6;
    const int lane = tid & 63;
    const int wr   = wave >> 1;
    const int wc   = wave & 1;

    const int bid  = blockIdx.x;
    const int xcd  = bid & 7;
    const int u    = bid >> 3;
    const int rb   = xcd * 8 + (u & 7);
    const int cgrp = u >> 3;                   // 0..15
    const int brow = rb * 128;

    const int nct = meta[1] >> 7;              // padD / 128 col-tiles
    const int ntl = (nct > cgrp) ? (((nct - cgrp - 1) >> 4) + 1) : 0;
    if (ntl == 0) return;                      // uniform block exit, pre-barrier
    const int nsteps = ntl << 4;

    const int srow = lane >> 2;
    const int sg   = (lane & 3) ^ ((lane >> 3) & 3);
    const int rsel = lane & 15;
    const int koff = ((lane >> 4) ^ ((lane >> 1) & 3)) * 8;

    f32x4 acc[4][4];
    #pragma unroll
    for (int m = 0; m < 4; ++m)
        #pragma unroll
        for (int n = 0; n < 4; ++n)
            acc[m][n] = (f32x4){0.f, 0.f, 0.f, 0.f};

    auto stage = [&](int g) {
        const int buf = g & 1, t = g >> 4, kt = g & 15;
        const int bcol = (cgrp + t * 16) << 7;
        #pragma unroll
        for (int i = 0; i < 2; ++i) {
            const __hip_bfloat16* gA =
                A + (size_t)(brow + wave * 32 + i * 16 + srow) * DIM + kt * 32 + sg * 8;
            gload_lds16(gA, &Asm[buf][(wave * 32 + i * 16) * 32]);
            const __hip_bfloat16* gB =
                B + (size_t)(bcol + wave * 32 + i * 16 + srow) * DIM + kt * 32 + sg * 8;
            gload_lds16(gB, &Bsm[buf][(wave * 32 + i * 16) * 32]);
        }
    };

    auto body = [&](int buf) {
        bf16x8 a[4], b[4];
        #pragma unroll
        for (int m = 0; m < 4; ++m)
            a[m] = *reinterpret_cast<const bf16x8*>(
                &Asm[buf][(wr * 64 + m * 16 + rsel) * 32 + koff]);
        #pragma unroll
        for (int n = 0; n < 4; ++n)
            b[n] = *reinterpret_cast<const bf16x8*>(
                &Bsm[buf][(wc * 64 + n * 16 + rsel) * 32 + koff]);
        #pragma unroll
        for (int m = 0; m < 4; ++m)
            #pragma unroll
            for (int n = 0; n < 4; ++n)
                acc[m][n] = __builtin_amdgcn_mfma_f32_16x16x32_bf16(a[m], b[n], acc[m][n], 0, 0, 0);
    };

    auto epi = [&](int i) {
        const int bcol = (cgrp + i * 16) << 7;
        float aadj[4];
        #pragma unroll
        for (int n = 0; n < 4; ++n) aadj[n] = adj[bcol + wc * 64 + n * 16 + rsel];
        #pragma unroll
        for (int m = 0; m < 4; ++m) {
            #pragma unroll
            for (int r = 0; r < 4; ++r) {
                int lr = wr * 64 + m * 16 + (lane >> 4) * 4 + r;
                float part = 0.f;
                #pragma unroll
                for (int n = 0; n < 4; ++n)
                    part += __expf(acc[m][n][r] + aadj[n]);
                part += __shfl_xor(part, 1, 16);
                part += __shfl_xor(part, 2, 16);
                part += __shfl_xor(part, 4, 16);
                part += __shfl_xor(part, 8, 16);
                if (rsel == 0) tsum[wc][lr] = part;
            }
        }
        __syncthreads();
        if (tid < 128)
            atomicAdd(&row_sum[brow + tid], tsum[0][tid] + tsum[1][tid]);
        #pragma unroll
        for (int m = 0; m < 4; ++m)
            #pragma unroll
            for (int n = 0; n < 4; ++n)
                acc[m][n] = (f32x4){0.f, 0.f, 0.f, 0.f};
    };

    stage(0);
    __syncthreads();

    #pragma unroll 1
    for (int g = 0; g < nsteps; ++g) {
        if (g + 1 < nsteps) stage(g + 1);
        body(g & 1);
        if ((g & 15) == 15) epi(g >> 4);
        __syncthreads();                  // drains vmcnt: stage(g+1) ready
    }
}

// ---- final: loss = log(row_sum) - true_logit --------------------------------
__global__ void k_final(const float* __restrict__ row_sum,
                        const float* __restrict__ true_logit,
                        float* __restrict__ loss) {
    int i = blockIdx.x * blockDim.x + threadIdx.x;
    loss[i] = logf(row_sum[i]) - true_logit[i];
}

extern "C" void kernel_launch(void* const* d_in, const int* in_sizes, int n_in,
                              void* d_out, int out_size, void* d_ws, size_t ws_size,
                              hipStream_t stream) {
    const float* inputs  = (const float*)d_in[0];
    const int*   labels  = (const int*)d_in[1];
    const float* W       = (const float*)d_in[2];
    const float* bias    = (const float*)d_in[3];
    const int*   sampled = (const int*)d_in[4];
    float*       loss    = (float*)d_out;

    char* ws = (char*)d_ws;
    __hip_bfloat16* Abf = (__hip_bfloat16*)ws;                                  // 8 MiB
    __hip_bfloat16* Bbf = (__hip_bfloat16*)(ws + (size_t)BATCH * DIM * 2);      // 8 MiB
    size_t off = (size_t)(BATCH + NSAMP) * DIM * 2;
    float* adj        = (float*)(ws + off);            off += NSAMP * 4;        // 32 KiB
    float* true_logit = (float*)(ws + off);            off += BATCH * 4;        // 32 KiB
    float* row_sum    = (float*)(ws + off);            off += BATCH * 4;        // 32 KiB
    int*   hist       = (int*)(ws + off);              off += HBINS * 4;        // 196 KiB
    int*   btot       = (int*)(ws + off);              off += 256 * 4;
    int*   boff       = (int*)(ws + off);              off += 256 * 4;
    int*   meta       = (int*)(ws + off);              off += 16;
    int*   didx       = (int*)(ws + off);              off += NSAMP * 4;        // 32 KiB

    hipLaunchKernelGGL(k_zero,    dim3(HBINS / 1024), dim3(1024), 0, stream, hist);
    hipLaunchKernelGGL(k_hist,    dim3(NSAMP / 1024), dim3(1024), 0, stream, sampled, hist);
    hipLaunchKernelGGL(k_scan1,   dim3(256), dim3(256), 0, stream, hist, btot);
    hipLaunchKernelGGL(k_scan2,   dim3(1),   dim3(256), 0, stream, btot, boff, meta);
    hipLaunchKernelGGL(k_scatter, dim3(256), dim3(256), 0, stream, hist, boff, didx);
    hipLaunchKernelGGL(k_prep,    dim3(BATCH + NSAMP), dim3(128), 0, stream,
                       inputs, labels, W, bias, hist, didx, meta,
                       Abf, Bbf, adj, true_logit, row_sum);
    hipLaunchKernelGGL(k_gemm,    dim3(1024), dim3(256), 0, stream,
                       Abf, Bbf, adj, labels, meta, row_sum);
    hipLaunchKernelGGL(k_final,   dim3(BATCH / 256), dim3(256), 0, stream,
                       row_sum, true_logit, loss);
}